// Round 19
// baseline (323.458 us; speedup 1.0000x reference)
//
#include <hip/hip_runtime.h>
#include <math.h>

#define H 300
#define PP 5
#define NE 128         // rows (edges/nodes) per block tile
#define KC 32          // k per chunk (bf16)
#define NCH 10         // 320 / 32
#define ROWB 128       // bytes per LDS row: [hi 64B | lo 64B]
#define WTILE (320 * ROWB)     // full-image chunk stride: 40960 B
#define WHALF (160 * ROWB)     // per-block W half-tile: 20480 B
#define ATILE (NE * ROWB)      // 16384 B
#define NTHREADS 256
#define GT 512         // GEMM block threads (8 waves)

using short8 = __attribute__((ext_vector_type(8))) short;
using f32x4  = __attribute__((ext_vector_type(4))) float;

__device__ __forceinline__ float wsum64(float v) {
#pragma unroll
    for (int m = 32; m >= 1; m >>= 1) v += __shfl_xor(v, m, 64);
    return v;
}
__device__ __forceinline__ float wmax64(float v) {
#pragma unroll
    for (int m = 32; m >= 1; m >>= 1) v = fmaxf(v, __shfl_xor(v, m, 64));
    return v;
}
__device__ __forceinline__ float eluf(float x) { return x > 0.f ? x : expm1f(x); }

__device__ __forceinline__ unsigned short f2bf(float x) {
    unsigned int u = __float_as_uint(x);
    unsigned int r = u + 0x7FFF + ((u >> 16) & 1);
    return (unsigned short)(r >> 16);
}
__device__ __forceinline__ float bf2f(unsigned short h) {
    return __uint_as_float(((unsigned int)h) << 16);
}
// swizzled byte offset within a [rows][128B] LDS tile (hi|lo halves per row)
__device__ __forceinline__ int sw(int r, int kb) {
    return r * ROWB + (kb ^ ((r & 7) << 4));
}
// compiler-friendly split (producers: presplit/combine)
__device__ __forceinline__ void split4_bits(const float* v, uint2& ph, uint2& pl) {
    unsigned short hs[4], ls[4];
#pragma unroll
    for (int i = 0; i < 4; ++i) {
        hs[i] = f2bf(v[i]);
        ls[i] = f2bf(v[i] - bf2f(hs[i]));
    }
    ph = make_uint2((unsigned)hs[0] | ((unsigned)hs[1] << 16),
                    (unsigned)hs[2] | ((unsigned)hs[3] << 16));
    pl = make_uint2((unsigned)ls[0] | ((unsigned)ls[1] << 16),
                    (unsigned)ls[2] | ((unsigned)ls[3] << 16));
}
// HW cvt_pk split (hot path: k_gemm storeA) — RNE, matches bits variant
__device__ __forceinline__ void split4_cvt(const float* v, uint2& ph, uint2& pl) {
    unsigned h01, h23, l01, l23;
    asm("v_cvt_pk_bf16_f32 %0, %1, %2" : "=v"(h01) : "v"(v[0]), "v"(v[1]));
    asm("v_cvt_pk_bf16_f32 %0, %1, %2" : "=v"(h23) : "v"(v[2]), "v"(v[3]));
    float r0 = v[0] - __uint_as_float(h01 << 16);
    float r1 = v[1] - __uint_as_float(h01 & 0xffff0000u);
    float r2 = v[2] - __uint_as_float(h23 << 16);
    float r3 = v[3] - __uint_as_float(h23 & 0xffff0000u);
    asm("v_cvt_pk_bf16_f32 %0, %1, %2" : "=v"(l01) : "v"(r0), "v"(r1));
    asm("v_cvt_pk_bf16_f32 %0, %1, %2" : "=v"(l23) : "v"(r2), "v"(r3));
    ph = make_uint2(h01, h23);
    pl = make_uint2(l01, l23);
}
// async global->LDS 16B copy (dest = wave-uniform base + lane*16)
__device__ __forceinline__ void gload16(const void* g, void* lds) {
    __builtin_amdgcn_global_load_lds(
        (const __attribute__((address_space(1))) unsigned int*)g,
        (__attribute__((address_space(3))) unsigned int*)lds, 16, 0, 0);
}
#define SBAR() __builtin_amdgcn_s_barrier()
#define SCHED() __builtin_amdgcn_sched_barrier(0)
#define WAIT_LGKM() asm volatile("s_waitcnt lgkmcnt(0)" ::: "memory")
#define WAIT_VM0()  asm volatile("s_waitcnt vmcnt(0)" ::: "memory")
#define WAIT_VM4()  asm volatile("s_waitcnt vmcnt(4)" ::: "memory")
#define WAIT_VM5()  asm volatile("s_waitcnt vmcnt(5)" ::: "memory")

// ---- K1: prop_sim = softmax(instruction @ prop_embeds^T) ; grid=B, block=64
__global__ void k_prop_sim(const float* __restrict__ instr,
                           const float* __restrict__ pe,
                           float* __restrict__ prop_sim) {
    int b = blockIdx.x, lane = threadIdx.x;
    float dots[PP];
#pragma unroll
    for (int p = 0; p < PP; ++p) {
        float s = 0.f;
        for (int hh = lane; hh < H; hh += 64) s += instr[b * H + hh] * pe[p * H + hh];
        dots[p] = wsum64(s);
    }
    if (lane == 0) {
        float m = dots[0];
#pragma unroll
        for (int p = 1; p < PP; ++p) m = fmaxf(m, dots[p]);
        float e[PP], s = 0.f;
#pragma unroll
        for (int p = 0; p < PP; ++p) { e[p] = expf(dots[p] - m); s += e[p]; }
        float inv = 1.f / s;
#pragma unroll
        for (int p = 0; p < PP; ++p) prop_sim[b * PP + p] = e[p] * inv;
    }
}

// ---- K2: histogram of node_indices
__global__ void k_counts(const int* __restrict__ idx, int* __restrict__ counts, int N) {
    int i = blockIdx.x * blockDim.x + threadIdx.x;
    if (i < N) atomicAdd(&counts[idx[i]], 1);
}

// ---- K3: exclusive scan -> segment offsets (B<=256), 1 block of 256
__global__ void k_scan(const int* __restrict__ counts, int* __restrict__ offsets, int B) {
    __shared__ int sh[256];
    int t = threadIdx.x;
    int c = (t < B) ? counts[t] : 0;
    sh[t] = c;
    __syncthreads();
    for (int off = 1; off < 256; off <<= 1) {
        int v = (t >= off) ? sh[t - off] : 0;
        __syncthreads();
        sh[t] += v;
        __syncthreads();
    }
    if (t < B) offsets[t] = sh[t] - c;
    if (t == B - 1) offsets[B] = sh[t];
}

// ---- P1: static edge-W (Ws[4]) -> pre-swizzled bf16 hi/lo LDS image
__global__ void k_presplit(const float* __restrict__ W4, char* __restrict__ img) {
    int c = blockIdx.x;
    int idx = blockIdx.y * NTHREADS + threadIdx.x;   // [0, 2560)
    int r = idx >> 3, j = idx & 7;
    int k = c * KC + j * 4;
    float v[4] = {0.f, 0.f, 0.f, 0.f};
    if (r < H && k < H) *(float4*)v = *(const float4*)&W4[(size_t)r * H + k];
    uint2 ph, pl;
    split4_bits(v, ph, pl);
    char* row = img + (size_t)c * WTILE + (size_t)r * ROWB;
    int x = (r & 7) << 4;
    *(uint2*)(row + ((j * 8) ^ x)) = ph;
    *(uint2*)(row + ((64 + j * 8) ^ x)) = pl;
}

// ---- P2: per-batch combined node-W (with instr row-fold) -> pre-swizzled image
// cv[h,k] = instr[b,h] * sum_p ps[b,p] * Ws[p][h,k]   (exact row-scalar fold)
__global__ void k_combine(const float* __restrict__ Ws,
                          const float* __restrict__ prop_sim,
                          const float* __restrict__ instr,
                          char* __restrict__ img) {
    int b = blockIdx.x, c = blockIdx.y, t = threadIdx.x;
    float ps0 = prop_sim[b * PP + 0], ps1 = prop_sim[b * PP + 1];
    float ps2 = prop_sim[b * PP + 2], ps3 = prop_sim[b * PP + 3];
    char* tile = img + ((size_t)b * NCH + c) * WTILE;
#pragma unroll
    for (int i = 0; i < 10; ++i) {
        int idx = t + i * NTHREADS;                  // [0, 2560)
        int r = idx >> 3, j = idx & 7;
        int k = c * KC + j * 4;
        float cv[4] = {0.f, 0.f, 0.f, 0.f};
        if (r < H && k < H) {
            float insv = instr[(size_t)b * H + r];
            size_t base = (size_t)r * H + k;
            float w0[4], w1[4], w2[4], w3[4];
            *(float4*)w0 = *(const float4*)&Ws[0 * (size_t)H * H + base];
            *(float4*)w1 = *(const float4*)&Ws[1 * (size_t)H * H + base];
            *(float4*)w2 = *(const float4*)&Ws[2 * (size_t)H * H + base];
            *(float4*)w3 = *(const float4*)&Ws[3 * (size_t)H * H + base];
#pragma unroll
            for (int q = 0; q < 4; ++q)
                cv[q] = insv * fmaf(ps0, w0[q], fmaf(ps1, w1[q], fmaf(ps2, w2[q], ps3 * w3[q])));
        }
        uint2 ph, pl;
        split4_bits(cv, ph, pl);
        char* row = tile + (size_t)r * ROWB;
        int x = (r & 7) << 4;
        *(uint2*)(row + ((j * 8) ^ x)) = ph;
        *(uint2*)(row + ((64 + j * 8) ^ x)) = pl;
    }
}

// ======================= fused MFMA GEMM (node + edge) =======================
// 1-D grid, locality-swizzled (R13/R14-proven: FETCH -43%).
// R19: barrier-separated fine phases (T3) + setprio (T5) on R16's W-dbuf +
// A-dbuf base. Per chunk: b-frags once, then 5 phases of
// {read W-frag | staging piece -> s_barrier -> lgkmcnt(0) -> setprio MFMA x6
//  -> s_barrier}; DMA issue + counted vmcnt once per chunk (T4, never 0 in
// steady state).
__global__ __launch_bounds__(GT, 2) void k_gemm(
    const float* __restrict__ na, const float* __restrict__ ea,
    const char* __restrict__ Wc_img, const char* __restrict__ Wr_img,
    const float* __restrict__ instr, const float* __restrict__ wstate,
    const float* __restrict__ wrel,
    const int* __restrict__ offsets, const int* __restrict__ eb,
    const int* __restrict__ ei, const float* __restrict__ dist,
    float* __restrict__ slog, float* __restrict__ rlog,
    int N, int E, int nodeVX)
{
    __shared__ __align__(16) char W_t[2][WHALF];   // 40 KB
    __shared__ __align__(16) char A_t[2][ATILE];   // 32 KB  (72 KB total)

    int x = blockIdx.x;
    bool isNode = x < nodeVX;
    const float* Asrc;
    const char* Wsrc;
    int base, rowmax, b = 0, hz, nn = NE;
    if (isNode) {
        int gq = x / 48, r = x - gq * 48;
        int k = r >> 3;
        b = gq * 8 + (r & 7);
        int tile = k >> 1;
        hz = k & 1;
        int start = offsets[b], end = offsets[b + 1];
        base = start + tile * NE;
        if (base >= end) return;
        nn = min(NE, end - base);
        rowmax = N - 1;
        Asrc = na;
        Wsrc = Wc_img + (size_t)b * NCH * WTILE + (size_t)hz * WHALF;
    } else {
        int y = x - nodeVX;
        int gq = y / 16, r = y - gq * 16;
        int e = gq * 8 + (r & 7);
        hz = r >> 3;
        base = e * NE;
        rowmax = E - 1;
        Asrc = ea;
        Wsrc = Wr_img + (size_t)hz * WHALF;
    }

    int t = threadIdx.x;
    int w = t >> 6, l = t & 63, lane16 = l & 15, g = l >> 4;
    int wn = w & 3, wh = w >> 2;

    f32x4 acc[5][2];
#pragma unroll
    for (int ht = 0; ht < 5; ++ht)
#pragma unroll
        for (int cg = 0; cg < 2; ++cg) acc[ht][cg] = (f32x4){0.f, 0.f, 0.f, 0.f};

    float4 pa[2];     // A prefetch (f32, split at store time)

    auto loadA = [&](int c) {
#pragma unroll
        for (int i = 0; i < 2; ++i) {
            int idx = t + i * GT;                    // [0, 1024)
            int r = idx >> 3, j = idx & 7;
            int k = c * KC + j * 4;
            float4 v = {0.f, 0.f, 0.f, 0.f};
            if (k < H) {
                int row = min(base + r, rowmax);
                v = *(const float4*)&Asrc[(size_t)row * H + k];
            }
            pa[i] = v;
        }
    };
    auto storeApiece = [&](int i, int sel) {
        int idx = t + i * GT;
        int r = idx >> 3, j = idx & 7;
        float v[4] = {pa[i].x, pa[i].y, pa[i].z, pa[i].w};
        uint2 ph, pl;
        split4_cvt(v, ph, pl);
        *(uint2*)(A_t[sel] + sw(r, j * 8)) = ph;
        *(uint2*)(A_t[sel] + sw(r, 64 + j * 8)) = pl;
    };
    // 20 KB half-tile DMA: waves 0-7 cover 16KB (2 ops), waves 0-3 the last 4KB.
    auto gloadW = [&](int c, int sel) {
        const char* src = Wsrc + (size_t)c * WTILE;
        char* dst = W_t[sel];
        int off = w * 1024 + (l << 4);
        gload16(src + off, dst + off);
        gload16(src + 8192 + off, dst + 8192 + off);
        if (w < 4) gload16(src + 16384 + off, dst + 16384 + off);
    };

    // prologue: A(0) staged, W(0)->buf0, W(1)->buf1, pa=A(1) in flight
    loadA(0);
    gloadW(0, 0);
    storeApiece(0, 0);
    storeApiece(1, 0);
    loadA(1);
    gloadW(1, 1);
    SCHED();
    if (w < 4) { WAIT_VM5(); } else { WAIT_VM4(); }   // W(0) landed
    WAIT_LGKM();
    SBAR();
    SCHED();

    for (int c = 0; c < NCH; ++c) {
        int cur = c & 1;
        bool stage = (c + 1 < NCH);
        // b-frags for this chunk (drained at phase-0 lgkm)
        short8 bh[2], bl[2];
#pragma unroll
        for (int cg = 0; cg < 2; ++cg) {
            int brow = wn * 32 + cg * 16 + lane16;
            bh[cg] = *(const short8*)(A_t[cur] + sw(brow, g * 16));
            bl[cg] = *(const short8*)(A_t[cur] + sw(brow, 64 + g * 16));
        }
        // ---- 5 barrier-separated phases ----
#pragma unroll
        for (int ht = 0; ht < 5; ++ht) {
            int arow = wh * 80 + ht * 16 + lane16;
            short8 ah = *(const short8*)(W_t[cur] + sw(arow, g * 16));
            short8 al = *(const short8*)(W_t[cur] + sw(arow, 64 + g * 16));
            if (stage && ht == 1) storeApiece(0, cur ^ 1);
            if (stage && ht == 3) storeApiece(1, cur ^ 1);
            SCHED();
            SBAR();
            WAIT_LGKM();
            SCHED();
            __builtin_amdgcn_s_setprio(1);
#pragma unroll
            for (int cg = 0; cg < 2; ++cg) {
                acc[ht][cg] = __builtin_amdgcn_mfma_f32_16x16x32_bf16(ah, bh[cg], acc[ht][cg], 0, 0, 0);
                acc[ht][cg] = __builtin_amdgcn_mfma_f32_16x16x32_bf16(ah, bl[cg], acc[ht][cg], 0, 0, 0);
                acc[ht][cg] = __builtin_amdgcn_mfma_f32_16x16x32_bf16(al, bh[cg], acc[ht][cg], 0, 0, 0);
            }
            __builtin_amdgcn_s_setprio(0);
            SCHED();
            SBAR();
        }
        // ---- chunk boundary: DMA issue + counted wait (never 0 mid-loop) ----
        if (stage) {
            if (c + 2 < NCH) {
                loadA(c + 2);                 // 2 vmem (HBM)
                gloadW(c + 2, cur);           // 2-3 DMA into just-freed buffer
                SCHED();
                if (w < 4) { WAIT_VM5(); } else { WAIT_VM4(); }  // W(c+1) landed
            } else {
                WAIT_VM0();                   // tail: drain W(c+1)
            }
            SBAR();
            SCHED();
        }
    }

    // ---- epilogues (partial over this block's 160-h half) ----
    if (isNode) {
        // instr folded into W image: logit partial = sum wst[h]*elu(acc)
#pragma unroll
        for (int cg = 0; cg < 2; ++cg) {
            float part = 0.f;
#pragma unroll
            for (int ht = 0; ht < 5; ++ht) {
                int hb = hz * 160 + wh * 80 + ht * 16 + g * 4;
#pragma unroll
                for (int r = 0; r < 4; ++r) {
                    int h = hb + r;
                    if (h < H) part += wstate[h] * eluf(acc[ht][cg][r]);
                }
            }
            part += __shfl_xor(part, 16, 64);
            part += __shfl_xor(part, 32, 64);
            int col = wn * 32 + cg * 16 + lane16;
            if (l < 16 && col < nn) atomicAdd(&slog[base + col], part);
        }
    } else {
#pragma unroll
        for (int cg = 0; cg < 2; ++cg) {
            int e = base + wn * 32 + cg * 16 + lane16;
            int be = eb[e];
            const float* insb = instr + (size_t)be * H;
            float part = 0.f;
#pragma unroll
            for (int ht = 0; ht < 5; ++ht) {
                int hb = hz * 160 + wh * 80 + ht * 16 + g * 4;
#pragma unroll
                for (int r = 0; r < 4; ++r) {
                    int h = hb + r;
                    if (h < H) part += wrel[h] * eluf(insb[h] * acc[ht][cg][r]);
                }
            }
            part += __shfl_xor(part, 16, 64);
            part += __shfl_xor(part, 32, 64);
            if (l < 16) atomicAdd(&rlog[ei[E + e]], dist[ei[e]] * part);
        }
    }
}

// ---- K6: per-batch segment softmax x2 + blend -> next_distribution
__global__ void k_final(const float* __restrict__ slog, const float* __restrict__ rlog,
                        const float* __restrict__ prop_sim, const int* __restrict__ offsets,
                        float* __restrict__ out)
{
    int b = blockIdx.x;
    int s0 = offsets[b], e1 = offsets[b + 1];
    int t = threadIdx.x, wave = t >> 6, lane = t & 63;
    __shared__ float shA[4], shB[4];
    float mS = -3.0e38f, mR = -3.0e38f;
    for (int i = s0 + t; i < e1; i += 256) {
        mS = fmaxf(mS, slog[i]);
        mR = fmaxf(mR, rlog[i]);
    }
    mS = wmax64(mS); mR = wmax64(mR);
    if (lane == 0) { shA[wave] = mS; shB[wave] = mR; }
    __syncthreads();
    mS = fmaxf(fmaxf(shA[0], shA[1]), fmaxf(shA[2], shA[3]));
    mR = fmaxf(fmaxf(shB[0], shB[1]), fmaxf(shB[2], shB[3]));
    __syncthreads();
    float sS = 0.f, sR = 0.f;
    for (int i = s0 + t; i < e1; i += 256) {
        sS += expf(slog[i] - mS);
        sR += expf(rlog[i] - mR);
    }
    sS = wsum64(sS); sR = wsum64(sR);
    if (lane == 0) { shA[wave] = sS; shB[wave] = sR; }
    __syncthreads();
    sS = shA[0] + shA[1] + shA[2] + shA[3];
    sR = shB[0] + shB[1] + shB[2] + shB[3];
    float r = prop_sim[b * PP + (PP - 1)];
    float iS = 1.f / sS, iR = 1.f / sR;
    for (int i = s0 + t; i < e1; i += 256) {
        float ns = expf(slog[i] - mS) * iS;
        float nr = expf(rlog[i] - mR) * iR;
        out[i] = r * nr + (1.f - r) * ns;
    }
}

extern "C" void kernel_launch(void* const* d_in, const int* in_sizes, int n_in,
                              void* d_out, int out_size, void* d_ws, size_t ws_size,
                              hipStream_t stream) {
    (void)n_in; (void)out_size; (void)ws_size;
    const float* instruction  = (const float*)d_in[0];
    const float* distribution = (const float*)d_in[1];
    const float* node_attrs   = (const float*)d_in[2];
    const float* edge_attrs   = (const float*)d_in[3];
    const int*   node_indices = (const int*)d_in[4];
    const int*   edge_batch   = (const int*)d_in[5];
    const int*   edge_indices = (const int*)d_in[6];
    const float* prop_embeds  = (const float*)d_in[7];
    const float* Ws           = (const float*)d_in[8];
    const float* W_state      = (const float*)d_in[9];
    const float* W_rel        = (const float*)d_in[10];

    int B = in_sizes[0] / H;   // 256
    int N = in_sizes[1];       // 51200
    int E = in_sizes[5];       // 102400

    float* out = (float*)d_out;        // [0,N): next_distribution, [N,N+B*PP): prop_sim
    float* prop_sim = out + N;

    float* ws = (float*)d_ws;
    float* state_logits = ws;                          // N
    float* rel_logits   = ws + N;                      // N
    int*   offsets      = (int*)(ws + 2 * (size_t)N);  // B+1
    int*   counts       = offsets + (B + 1);           // B
    uintptr_t wsp = (uintptr_t)(counts + B);
    wsp = (wsp + 255) & ~(uintptr_t)255;
    char* Wr_img = (char*)wsp;                         // NCH*WTILE = 409600 B
    char* Wc_img = Wr_img + (size_t)NCH * WTILE;       // B*NCH*WTILE = 104.86 MB

    size_t zero_bytes = (size_t)2 * N * sizeof(float) + (size_t)(2 * B + 1) * sizeof(int);
    hipMemsetAsync(d_ws, 0, zero_bytes, stream);

    int nodeVX = 6 * B;                                // 1536 (3 tiles x 2 hz per b)
    int edgeVX = (E / NE) * 2;                         // 1600

    k_prop_sim<<<B, 64, 0, stream>>>(instruction, prop_embeds, prop_sim);
    k_presplit<<<dim3(NCH, 10), NTHREADS, 0, stream>>>(Ws + 4 * (size_t)H * H, Wr_img);
    k_counts<<<(N + 255) / 256, 256, 0, stream>>>(node_indices, counts, N);
    k_scan<<<1, 256, 0, stream>>>(counts, offsets, B);
    k_combine<<<dim3(B, NCH), NTHREADS, 0, stream>>>(Ws, prop_sim, instruction, Wc_img);
    k_gemm<<<nodeVX + edgeVX, GT, 0, stream>>>(
        node_attrs, edge_attrs, Wc_img, Wr_img, instruction, W_state, W_rel,
        offsets, edge_batch, edge_indices, distribution,
        state_logits, rel_logits, N, E, nodeVX);
    k_final<<<B, 256, 0, stream>>>(state_logits, rel_logits, prop_sim, offsets, out);
}

// Round 20
// 298.184 us; speedup vs baseline: 1.0848x; 1.0848x over previous
//
#include <hip/hip_runtime.h>
#include <math.h>

#define H 300
#define PP 5
#define NE 128         // rows (edges/nodes) per block tile
#define KC 32          // k per chunk (bf16)
#define NCH 10         // 320 / 32
#define ROWB 128       // bytes per LDS row: [hi 64B | lo 64B]
#define WTILE (320 * ROWB)     // full-image chunk stride: 40960 B
#define WHALF (160 * ROWB)     // per-block W half-tile: 20480 B
#define ATILE (NE * ROWB)      // 16384 B
#define NTHREADS 256
#define GT 512         // GEMM block threads (8 waves)

using short8 = __attribute__((ext_vector_type(8))) short;
using f32x4  = __attribute__((ext_vector_type(4))) float;

__device__ __forceinline__ float wsum64(float v) {
#pragma unroll
    for (int m = 32; m >= 1; m >>= 1) v += __shfl_xor(v, m, 64);
    return v;
}
__device__ __forceinline__ float wmax64(float v) {
#pragma unroll
    for (int m = 32; m >= 1; m >>= 1) v = fmaxf(v, __shfl_xor(v, m, 64));
    return v;
}
__device__ __forceinline__ float eluf(float x) { return x > 0.f ? x : expm1f(x); }

__device__ __forceinline__ unsigned short f2bf(float x) {
    unsigned int u = __float_as_uint(x);
    unsigned int r = u + 0x7FFF + ((u >> 16) & 1);
    return (unsigned short)(r >> 16);
}
__device__ __forceinline__ float bf2f(unsigned short h) {
    return __uint_as_float(((unsigned int)h) << 16);
}
// swizzled byte offset within a [rows][128B] LDS tile (hi|lo halves per row)
__device__ __forceinline__ int sw(int r, int kb) {
    return r * ROWB + (kb ^ ((r & 7) << 4));
}
// compiler-friendly split (producers: presplit/combine)
__device__ __forceinline__ void split4_bits(const float* v, uint2& ph, uint2& pl) {
    unsigned short hs[4], ls[4];
#pragma unroll
    for (int i = 0; i < 4; ++i) {
        hs[i] = f2bf(v[i]);
        ls[i] = f2bf(v[i] - bf2f(hs[i]));
    }
    ph = make_uint2((unsigned)hs[0] | ((unsigned)hs[1] << 16),
                    (unsigned)hs[2] | ((unsigned)hs[3] << 16));
    pl = make_uint2((unsigned)ls[0] | ((unsigned)ls[1] << 16),
                    (unsigned)ls[2] | ((unsigned)ls[3] << 16));
}
// HW cvt_pk split (hot path: k_gemm storeA) — RNE, matches bits variant
__device__ __forceinline__ void split4_cvt(const float* v, uint2& ph, uint2& pl) {
    unsigned h01, h23, l01, l23;
    asm("v_cvt_pk_bf16_f32 %0, %1, %2" : "=v"(h01) : "v"(v[0]), "v"(v[1]));
    asm("v_cvt_pk_bf16_f32 %0, %1, %2" : "=v"(h23) : "v"(v[2]), "v"(v[3]));
    float r0 = v[0] - __uint_as_float(h01 << 16);
    float r1 = v[1] - __uint_as_float(h01 & 0xffff0000u);
    float r2 = v[2] - __uint_as_float(h23 << 16);
    float r3 = v[3] - __uint_as_float(h23 & 0xffff0000u);
    asm("v_cvt_pk_bf16_f32 %0, %1, %2" : "=v"(l01) : "v"(r0), "v"(r1));
    asm("v_cvt_pk_bf16_f32 %0, %1, %2" : "=v"(l23) : "v"(r2), "v"(r3));
    ph = make_uint2(h01, h23);
    pl = make_uint2(l01, l23);
}
// async global->LDS 16B copy (dest = wave-uniform base + lane*16)
__device__ __forceinline__ void gload16(const void* g, void* lds) {
    __builtin_amdgcn_global_load_lds(
        (const __attribute__((address_space(1))) unsigned int*)g,
        (__attribute__((address_space(3))) unsigned int*)lds, 16, 0, 0);
}
#define SBAR() __builtin_amdgcn_s_barrier()
#define SCHED() __builtin_amdgcn_sched_barrier(0)
#define WAIT_LGKM() asm volatile("s_waitcnt lgkmcnt(0)" ::: "memory")
#define WAIT_VM0()  asm volatile("s_waitcnt vmcnt(0)" ::: "memory")
#define WAIT_VM4()  asm volatile("s_waitcnt vmcnt(4)" ::: "memory")
#define WAIT_VM5()  asm volatile("s_waitcnt vmcnt(5)" ::: "memory")

// ---- K1: prop_sim = softmax(instruction @ prop_embeds^T) ; grid=B, block=64
__global__ void k_prop_sim(const float* __restrict__ instr,
                           const float* __restrict__ pe,
                           float* __restrict__ prop_sim) {
    int b = blockIdx.x, lane = threadIdx.x;
    float dots[PP];
#pragma unroll
    for (int p = 0; p < PP; ++p) {
        float s = 0.f;
        for (int hh = lane; hh < H; hh += 64) s += instr[b * H + hh] * pe[p * H + hh];
        dots[p] = wsum64(s);
    }
    if (lane == 0) {
        float m = dots[0];
#pragma unroll
        for (int p = 1; p < PP; ++p) m = fmaxf(m, dots[p]);
        float e[PP], s = 0.f;
#pragma unroll
        for (int p = 0; p < PP; ++p) { e[p] = expf(dots[p] - m); s += e[p]; }
        float inv = 1.f / s;
#pragma unroll
        for (int p = 0; p < PP; ++p) prop_sim[b * PP + p] = e[p] * inv;
    }
}

// ---- K2: histogram of node_indices
__global__ void k_counts(const int* __restrict__ idx, int* __restrict__ counts, int N) {
    int i = blockIdx.x * blockDim.x + threadIdx.x;
    if (i < N) atomicAdd(&counts[idx[i]], 1);
}

// ---- K3: exclusive scan -> segment offsets (B<=256), 1 block of 256
__global__ void k_scan(const int* __restrict__ counts, int* __restrict__ offsets, int B) {
    __shared__ int sh[256];
    int t = threadIdx.x;
    int c = (t < B) ? counts[t] : 0;
    sh[t] = c;
    __syncthreads();
    for (int off = 1; off < 256; off <<= 1) {
        int v = (t >= off) ? sh[t - off] : 0;
        __syncthreads();
        sh[t] += v;
        __syncthreads();
    }
    if (t < B) offsets[t] = sh[t] - c;
    if (t == B - 1) offsets[B] = sh[t];
}

// ---- P1: static edge-W (Ws[4]) -> pre-swizzled bf16 hi/lo LDS image
__global__ void k_presplit(const float* __restrict__ W4, char* __restrict__ img) {
    int c = blockIdx.x;
    int idx = blockIdx.y * NTHREADS + threadIdx.x;   // [0, 2560)
    int r = idx >> 3, j = idx & 7;
    int k = c * KC + j * 4;
    float v[4] = {0.f, 0.f, 0.f, 0.f};
    if (r < H && k < H) *(float4*)v = *(const float4*)&W4[(size_t)r * H + k];
    uint2 ph, pl;
    split4_bits(v, ph, pl);
    char* row = img + (size_t)c * WTILE + (size_t)r * ROWB;
    int x = (r & 7) << 4;
    *(uint2*)(row + ((j * 8) ^ x)) = ph;
    *(uint2*)(row + ((64 + j * 8) ^ x)) = pl;
}

// ---- P2: per-batch combined node-W (with instr row-fold) -> pre-swizzled image
// cv[h,k] = instr[b,h] * sum_p ps[b,p] * Ws[p][h,k]   (exact row-scalar fold)
__global__ void k_combine(const float* __restrict__ Ws,
                          const float* __restrict__ prop_sim,
                          const float* __restrict__ instr,
                          char* __restrict__ img) {
    int b = blockIdx.x, c = blockIdx.y, t = threadIdx.x;
    float ps0 = prop_sim[b * PP + 0], ps1 = prop_sim[b * PP + 1];
    float ps2 = prop_sim[b * PP + 2], ps3 = prop_sim[b * PP + 3];
    char* tile = img + ((size_t)b * NCH + c) * WTILE;
#pragma unroll
    for (int i = 0; i < 10; ++i) {
        int idx = t + i * NTHREADS;                  // [0, 2560)
        int r = idx >> 3, j = idx & 7;
        int k = c * KC + j * 4;
        float cv[4] = {0.f, 0.f, 0.f, 0.f};
        if (r < H && k < H) {
            float insv = instr[(size_t)b * H + r];
            size_t base = (size_t)r * H + k;
            float w0[4], w1[4], w2[4], w3[4];
            *(float4*)w0 = *(const float4*)&Ws[0 * (size_t)H * H + base];
            *(float4*)w1 = *(const float4*)&Ws[1 * (size_t)H * H + base];
            *(float4*)w2 = *(const float4*)&Ws[2 * (size_t)H * H + base];
            *(float4*)w3 = *(const float4*)&Ws[3 * (size_t)H * H + base];
#pragma unroll
            for (int q = 0; q < 4; ++q)
                cv[q] = insv * fmaf(ps0, w0[q], fmaf(ps1, w1[q], fmaf(ps2, w2[q], ps3 * w3[q])));
        }
        uint2 ph, pl;
        split4_bits(cv, ph, pl);
        char* row = tile + (size_t)r * ROWB;
        int x = (r & 7) << 4;
        *(uint2*)(row + ((j * 8) ^ x)) = ph;
        *(uint2*)(row + ((64 + j * 8) ^ x)) = pl;
    }
}

// ======================= fused MFMA GEMM (node + edge) =======================
// R16 configuration (best measured: 298.2 us total, k_gemm ~218 us).
// 1-D grid, locality-swizzled (FETCH -43%):
//  nodes: x = (b/8)*48 + (tile*2+hz)*8 + (b%8),  x < nodeVX = 6*B
//  edges: x = nodeVX + (e/8)*16 + hz*8 + (e%8)
// A AND W double-buffered: storeA folds into the compute phase (overlaps
// MFMA); inter-barrier region is only DMA-issue + counted vmwait (T4,
// never 0 in steady state). Monolithic compute (compiler-scheduled).
// NO min-waves directive beyond 2 (R7/R10/R17 lesson: tight bounds spill).
__global__ __launch_bounds__(GT, 2) void k_gemm(
    const float* __restrict__ na, const float* __restrict__ ea,
    const char* __restrict__ Wc_img, const char* __restrict__ Wr_img,
    const float* __restrict__ instr, const float* __restrict__ wstate,
    const float* __restrict__ wrel,
    const int* __restrict__ offsets, const int* __restrict__ eb,
    const int* __restrict__ ei, const float* __restrict__ dist,
    float* __restrict__ slog, float* __restrict__ rlog,
    int N, int E, int nodeVX)
{
    __shared__ __align__(16) char W_t[2][WHALF];   // 40 KB
    __shared__ __align__(16) char A_t[2][ATILE];   // 32 KB  (72 KB total)

    int x = blockIdx.x;
    bool isNode = x < nodeVX;
    const float* Asrc;
    const char* Wsrc;
    int base, rowmax, b = 0, hz, nn = NE;
    if (isNode) {
        int gq = x / 48, r = x - gq * 48;
        int k = r >> 3;
        b = gq * 8 + (r & 7);
        int tile = k >> 1;
        hz = k & 1;
        int start = offsets[b], end = offsets[b + 1];
        base = start + tile * NE;
        if (base >= end) return;
        nn = min(NE, end - base);
        rowmax = N - 1;
        Asrc = na;
        Wsrc = Wc_img + (size_t)b * NCH * WTILE + (size_t)hz * WHALF;
    } else {
        int y = x - nodeVX;
        int gq = y / 16, r = y - gq * 16;
        int e = gq * 8 + (r & 7);
        hz = r >> 3;
        base = e * NE;
        rowmax = E - 1;
        Asrc = ea;
        Wsrc = Wr_img + (size_t)hz * WHALF;
    }

    int t = threadIdx.x;
    int w = t >> 6, l = t & 63, lane16 = l & 15, g = l >> 4;
    int wn = w & 3, wh = w >> 2;

    f32x4 acc[5][2];
#pragma unroll
    for (int ht = 0; ht < 5; ++ht)
#pragma unroll
        for (int cg = 0; cg < 2; ++cg) acc[ht][cg] = (f32x4){0.f, 0.f, 0.f, 0.f};

    float4 pa[2];     // A prefetch (f32, split at store time)

    auto loadA = [&](int c) {
#pragma unroll
        for (int i = 0; i < 2; ++i) {
            int idx = t + i * GT;                    // [0, 1024)
            int r = idx >> 3, j = idx & 7;
            int k = c * KC + j * 4;
            float4 v = {0.f, 0.f, 0.f, 0.f};
            if (k < H) {
                int row = min(base + r, rowmax);
                v = *(const float4*)&Asrc[(size_t)row * H + k];
            }
            pa[i] = v;
        }
    };
    auto storeA = [&](int sel) {
#pragma unroll
        for (int i = 0; i < 2; ++i) {
            int idx = t + i * GT;
            int r = idx >> 3, j = idx & 7;
            float v[4] = {pa[i].x, pa[i].y, pa[i].z, pa[i].w};
            uint2 ph, pl;
            split4_cvt(v, ph, pl);
            *(uint2*)(A_t[sel] + sw(r, j * 8)) = ph;
            *(uint2*)(A_t[sel] + sw(r, 64 + j * 8)) = pl;
        }
    };
    // 20 KB half-tile DMA: waves 0-7 cover 16KB (2 ops), waves 0-3 the last 4KB.
    auto gloadW = [&](int c, int sel) {
        const char* src = Wsrc + (size_t)c * WTILE;
        char* dst = W_t[sel];
        int off = w * 1024 + (l << 4);
        gload16(src + off, dst + off);
        gload16(src + 8192 + off, dst + 8192 + off);
        if (w < 4) gload16(src + 16384 + off, dst + 16384 + off);
    };

    // prologue: A(0) staged, W(0)->buf0, W(1)->buf1, pa=A(1) in flight
    loadA(0);
    gloadW(0, 0);
    storeA(0);                // compiler-counted wait drains only pa(0)
    loadA(1);
    gloadW(1, 1);
    SCHED();
    if (w < 4) { WAIT_VM5(); } else { WAIT_VM4(); }   // W(0) landed
    WAIT_LGKM();
    SBAR();
    SCHED();

    for (int c = 0; c < NCH; ++c) {
        int cur = c & 1;
        // ---- compute chunk c + overlapped A-staging for c+1 ----
        short8 bh[2], bl[2];
#pragma unroll
        for (int cg = 0; cg < 2; ++cg) {
            int brow = wn * 32 + cg * 16 + lane16;
            bh[cg] = *(const short8*)(A_t[cur] + sw(brow, g * 16));
            bl[cg] = *(const short8*)(A_t[cur] + sw(brow, 64 + g * 16));
        }
#pragma unroll
        for (int ht = 0; ht < 5; ++ht) {
            int arow = wh * 80 + ht * 16 + lane16;
            short8 ah = *(const short8*)(W_t[cur] + sw(arow, g * 16));
            short8 al = *(const short8*)(W_t[cur] + sw(arow, 64 + g * 16));
#pragma unroll
            for (int cg = 0; cg < 2; ++cg) {
                acc[ht][cg] = __builtin_amdgcn_mfma_f32_16x16x32_bf16(ah, bh[cg], acc[ht][cg], 0, 0, 0);
                acc[ht][cg] = __builtin_amdgcn_mfma_f32_16x16x32_bf16(ah, bl[cg], acc[ht][cg], 0, 0, 0);
                acc[ht][cg] = __builtin_amdgcn_mfma_f32_16x16x32_bf16(al, bh[cg], acc[ht][cg], 0, 0, 0);
            }
        }
        if (c + 1 < NCH) {
            storeA(cur ^ 1);                  // pa(c+1) -> other A buffer (no race)
            if (c + 2 < NCH) loadA(c + 2);    // issue next A loads early
            WAIT_LGKM();                      // own reads of cur + writes done
            SBAR();                           // #1: all reads of buf[cur] done
            SCHED();
            if (c + 2 < NCH) {
                gloadW(c + 2, cur);           // DMA into just-freed W buffer
                SCHED();
                if (w < 4) { WAIT_VM5(); } else { WAIT_VM4(); }  // W(c+1) landed
            } else {
                WAIT_VM0();                   // tail: drain W(c+1)
            }
            SBAR();                           // #2: W(c+1) landing collective
            SCHED();
        }
    }

    // ---- epilogues (partial over this block's 160-h half) ----
    if (isNode) {
        // instr folded into W image: logit partial = sum wst[h]*elu(acc)
#pragma unroll
        for (int cg = 0; cg < 2; ++cg) {
            float part = 0.f;
#pragma unroll
            for (int ht = 0; ht < 5; ++ht) {
                int hb = hz * 160 + wh * 80 + ht * 16 + g * 4;
#pragma unroll
                for (int r = 0; r < 4; ++r) {
                    int h = hb + r;
                    if (h < H) part += wstate[h] * eluf(acc[ht][cg][r]);
                }
            }
            part += __shfl_xor(part, 16, 64);
            part += __shfl_xor(part, 32, 64);
            int col = wn * 32 + cg * 16 + lane16;
            if (l < 16 && col < nn) atomicAdd(&slog[base + col], part);
        }
    } else {
#pragma unroll
        for (int cg = 0; cg < 2; ++cg) {
            int e = base + wn * 32 + cg * 16 + lane16;
            int be = eb[e];
            const float* insb = instr + (size_t)be * H;
            float part = 0.f;
#pragma unroll
            for (int ht = 0; ht < 5; ++ht) {
                int hb = hz * 160 + wh * 80 + ht * 16 + g * 4;
#pragma unroll
                for (int r = 0; r < 4; ++r) {
                    int h = hb + r;
                    if (h < H) part += wrel[h] * eluf(insb[h] * acc[ht][cg][r]);
                }
            }
            part += __shfl_xor(part, 16, 64);
            part += __shfl_xor(part, 32, 64);
            if (l < 16) atomicAdd(&rlog[ei[E + e]], dist[ei[e]] * part);
        }
    }
}

// ---- K6: per-batch segment softmax x2 + blend -> next_distribution
__global__ void k_final(const float* __restrict__ slog, const float* __restrict__ rlog,
                        const float* __restrict__ prop_sim, const int* __restrict__ offsets,
                        float* __restrict__ out)
{
    int b = blockIdx.x;
    int s0 = offsets[b], e1 = offsets[b + 1];
    int t = threadIdx.x, wave = t >> 6, lane = t & 63;
    __shared__ float shA[4], shB[4];
    float mS = -3.0e38f, mR = -3.0e38f;
    for (int i = s0 + t; i < e1; i += 256) {
        mS = fmaxf(mS, slog[i]);
        mR = fmaxf(mR, rlog[i]);
    }
    mS = wmax64(mS); mR = wmax64(mR);
    if (lane == 0) { shA[wave] = mS; shB[wave] = mR; }
    __syncthreads();
    mS = fmaxf(fmaxf(shA[0], shA[1]), fmaxf(shA[2], shA[3]));
    mR = fmaxf(fmaxf(shB[0], shB[1]), fmaxf(shB[2], shB[3]));
    __syncthreads();
    float sS = 0.f, sR = 0.f;
    for (int i = s0 + t; i < e1; i += 256) {
        sS += expf(slog[i] - mS);
        sR += expf(rlog[i] - mR);
    }
    sS = wsum64(sS); sR = wsum64(sR);
    if (lane == 0) { shA[wave] = sS; shB[wave] = sR; }
    __syncthreads();
    sS = shA[0] + shA[1] + shA[2] + shA[3];
    sR = shB[0] + shB[1] + shB[2] + shB[3];
    float r = prop_sim[b * PP + (PP - 1)];
    float iS = 1.f / sS, iR = 1.f / sR;
    for (int i = s0 + t; i < e1; i += 256) {
        float ns = expf(slog[i] - mS) * iS;
        float nr = expf(rlog[i] - mR) * iR;
        out[i] = r * nr + (1.f - r) * ns;
    }
}

extern "C" void kernel_launch(void* const* d_in, const int* in_sizes, int n_in,
                              void* d_out, int out_size, void* d_ws, size_t ws_size,
                              hipStream_t stream) {
    (void)n_in; (void)out_size; (void)ws_size;
    const float* instruction  = (const float*)d_in[0];
    const float* distribution = (const float*)d_in[1];
    const float* node_attrs   = (const float*)d_in[2];
    const float* edge_attrs   = (const float*)d_in[3];
    const int*   node_indices = (const int*)d_in[4];
    const int*   edge_batch   = (const int*)d_in[5];
    const int*   edge_indices = (const int*)d_in[6];
    const float* prop_embeds  = (const float*)d_in[7];
    const float* Ws           = (const float*)d_in[8];
    const float* W_state      = (const float*)d_in[9];
    const float* W_rel        = (const float*)d_in[10];

    int B = in_sizes[0] / H;   // 256
    int N = in_sizes[1];       // 51200
    int E = in_sizes[5];       // 102400

    float* out = (float*)d_out;        // [0,N): next_distribution, [N,N+B*PP): prop_sim
    float* prop_sim = out + N;

    float* ws = (float*)d_ws;
    float* state_logits = ws;                          // N
    float* rel_logits   = ws + N;                      // N
    int*   offsets      = (int*)(ws + 2 * (size_t)N);  // B+1
    int*   counts       = offsets + (B + 1);           // B
    uintptr_t wsp = (uintptr_t)(counts + B);
    wsp = (wsp + 255) & ~(uintptr_t)255;
    char* Wr_img = (char*)wsp;                         // NCH*WTILE = 409600 B
    char* Wc_img = Wr_img + (size_t)NCH * WTILE;       // B*NCH*WTILE = 104.86 MB

    size_t zero_bytes = (size_t)2 * N * sizeof(float) + (size_t)(2 * B + 1) * sizeof(int);
    hipMemsetAsync(d_ws, 0, zero_bytes, stream);

    int nodeVX = 6 * B;                                // 1536 (3 tiles x 2 hz per b)
    int edgeVX = (E / NE) * 2;                         // 1600

    k_prop_sim<<<B, 64, 0, stream>>>(instruction, prop_embeds, prop_sim);
    k_presplit<<<dim3(NCH, 10), NTHREADS, 0, stream>>>(Ws + 4 * (size_t)H * H, Wr_img);
    k_counts<<<(N + 255) / 256, 256, 0, stream>>>(node_indices, counts, N);
    k_scan<<<1, 256, 0, stream>>>(counts, offsets, B);
    k_combine<<<dim3(B, NCH), NTHREADS, 0, stream>>>(Ws, prop_sim, instruction, Wc_img);
    k_gemm<<<nodeVX + edgeVX, GT, 0, stream>>>(
        node_attrs, edge_attrs, Wc_img, Wr_img, instruction, W_state, W_rel,
        offsets, edge_batch, edge_indices, distribution,
        state_logits, rel_logits, N, E, nodeVX);
    k_final<<<B, 256, 0, stream>>>(state_logits, rel_logits, prop_sim, offsets, out);
}